// Round 1
// baseline (2907.256 us; speedup 1.0000x reference)
//
#include <hip/hip_runtime.h>

#define DIMD 256
#define PDIM 256
#define NB   8
#define LSEQ 4096
#define MTOT (NB*LSEQ)      // 32768
#define FDIM 2560
#define NCHUNK 64
#define CLEN 64

// ---- workspace layout (float offsets) ----
static const size_t OFF_LBR  = 0;      // lam_bar re           [256]
static const size_t OFF_LBI  = 256;    // lam_bar im
static const size_t OFF_A64R = 512;    // lam_bar^64 re
static const size_t OFF_A64I = 768;
static const size_t OFF_WR   = 1024;   // w = B_bar . l1_w
static const size_t OFF_WI   = 1280;
static const size_t OFF_CR   = 1536;   // c = B_bar . l1_b
static const size_t OFF_CI   = 1792;
static const size_t OFF_E_RE   = 4096;                       // chunk end states [8][64][256]
static const size_t OFF_E_IM   = OFF_E_RE   + 131072;
static const size_t OFF_CAR_RE = OFF_E_IM   + 131072;        // chunk carry-in   [8][64][256]
static const size_t OFF_CAR_IM = OFF_CAR_RE + 131072;
static const size_t OFF_XS_RE  = OFF_CAR_IM + 131072;        // xs re [32768][256]
static const size_t OFF_XS_IM  = OFF_XS_RE  + 8388608;
static const size_t OFF_H1     = OFF_XS_IM  + 8388608;       // h1    [32768][256]
static const size_t OFF_DWT    = OFF_H1     + 8388608;       // dec_w^T [2560][256]
// total = 26,349,568 floats = 105.4 MB

// ---- per-p constants: lam_bar, lam_bar^64, w, c ----
__global__ void k_consts(const float* __restrict__ l1w, const float* __restrict__ l1b,
                         const float* __restrict__ lam_re, const float* __restrict__ lam_im,
                         const float* __restrict__ B_re, const float* __restrict__ B_im,
                         const float* __restrict__ log_step, float* __restrict__ ws) {
    int p = threadIdx.x;
    float st = expf(log_step[p]);
    float lr = lam_re[p], li = lam_im[p];
    float zr = lr * st, zi = li * st;
    float er = expf(zr);
    float lbr = er * cosf(zi), lbi = er * sinf(zi);
    // fac = (lam_bar - 1)/lam
    float den = lr * lr + li * li;
    float nr = lbr - 1.0f, ni = lbi;
    float facr = (nr * lr + ni * li) / den;
    float faci = (ni * lr - nr * li) / den;
    // dots over h
    float dwr = 0.f, dwi = 0.f, dbr = 0.f, dbi = 0.f;
    for (int h = 0; h < DIMD; ++h) {
        float br = B_re[p * DIMD + h], bi = B_im[p * DIMD + h];
        float w1 = l1w[h], b1 = l1b[h];
        dwr = fmaf(br, w1, dwr); dwi = fmaf(bi, w1, dwi);
        dbr = fmaf(br, b1, dbr); dbi = fmaf(bi, b1, dbi);
    }
    float wr = facr * dwr - faci * dwi, wi = facr * dwi + faci * dwr;
    float cr = facr * dbr - faci * dbi, ci = facr * dbi + faci * dbr;
    // lam_bar^64 by 6 squarings
    float ar = lbr, ai = lbi;
    for (int s = 0; s < 6; ++s) { float t = ar * ar - ai * ai; ai = 2.f * ar * ai; ar = t; }
    ws[OFF_LBR + p] = lbr;  ws[OFF_LBI + p] = lbi;
    ws[OFF_A64R + p] = ar;  ws[OFF_A64I + p] = ai;
    ws[OFF_WR + p] = wr;    ws[OFF_WI + p] = wi;
    ws[OFF_CR + p] = cr;    ws[OFF_CI + p] = ci;
}

// ---- transpose dec_w [256][2560] -> dwt [2560][256] ----
__global__ void k_transpose(const float* __restrict__ dec_w, float* __restrict__ dwt) {
    __shared__ float tile[32][33];
    int bx = blockIdx.x;   // k tile (80)
    int by = blockIdx.y;   // n tile (8)
    int t = threadIdx.x;
    int lr = t >> 5, lc = t & 31;
    #pragma unroll
    for (int s = 0; s < 4; ++s)
        tile[lr + s * 8][lc] = dec_w[(size_t)(by * 32 + lr + s * 8) * FDIM + bx * 32 + lc];
    __syncthreads();
    #pragma unroll
    for (int s = 0; s < 4; ++s)
        dwt[(size_t)(bx * 32 + lr + s * 8) * DIMD + by * 32 + lc] = tile[lc][lr + s * 8];
}

// ---- scan pass A: per (b,chunk,p) compute chunk-local end state (zero init) ----
__global__ void k_scanA(const float* __restrict__ x, float* __restrict__ ws) {
    int p = threadIdx.x, chunk = blockIdx.x, b = blockIdx.y;
    float lbr = ws[OFF_LBR + p], lbi = ws[OFF_LBI + p];
    float wr = ws[OFF_WR + p], wi = ws[OFF_WI + p];
    float cr = ws[OFF_CR + p], ci = ws[OFF_CI + p];
    const float* xb = x + (size_t)b * LSEQ + chunk * CLEN;
    float sr = 0.f, si = 0.f;
    for (int t = 0; t < CLEN; ++t) {
        float xv = xb[t];
        float bur = fmaf(xv, wr, cr), bui = fmaf(xv, wi, ci);
        float nsr = fmaf(lbr, sr, fmaf(-lbi, si, bur));
        float nsi = fmaf(lbr, si, fmaf(lbi, sr, bui));
        sr = nsr; si = nsi;
    }
    size_t idx = ((size_t)b * NCHUNK + chunk) * PDIM + p;
    ws[OFF_E_RE + idx] = sr; ws[OFF_E_IM + idx] = si;
}

// ---- scan pass B: per (b,p) combine chunks sequentially, store carry-in per chunk ----
__global__ void k_scanB(float* __restrict__ ws) {
    int p = threadIdx.x, b = blockIdx.x;
    float ar = ws[OFF_A64R + p], ai = ws[OFF_A64I + p];
    float sr = 0.f, si = 0.f;
    for (int c = 0; c < NCHUNK; ++c) {
        size_t idx = ((size_t)b * NCHUNK + c) * PDIM + p;
        ws[OFF_CAR_RE + idx] = sr; ws[OFF_CAR_IM + idx] = si;
        float er = ws[OFF_E_RE + idx], ei = ws[OFF_E_IM + idx];
        float nsr = fmaf(ar, sr, fmaf(-ai, si, er));
        float nsi = fmaf(ar, si, fmaf(ai, sr, ei));
        sr = nsr; si = nsi;
    }
}

// ---- scan pass C: recompute local scan with carry, write xs ----
__global__ void k_scanC(const float* __restrict__ x, float* __restrict__ ws) {
    int p = threadIdx.x, chunk = blockIdx.x, b = blockIdx.y;
    float lbr = ws[OFF_LBR + p], lbi = ws[OFF_LBI + p];
    float wr = ws[OFF_WR + p], wi = ws[OFF_WI + p];
    float cr = ws[OFF_CR + p], ci = ws[OFF_CI + p];
    size_t cidx = ((size_t)b * NCHUNK + chunk) * PDIM + p;
    float sr = ws[OFF_CAR_RE + cidx], si = ws[OFF_CAR_IM + cidx];
    const float* xb = x + (size_t)b * LSEQ + chunk * CLEN;
    size_t row0 = (size_t)b * LSEQ + chunk * CLEN;
    float* xr = ws + OFF_XS_RE;
    float* xi = ws + OFF_XS_IM;
    for (int t = 0; t < CLEN; ++t) {
        float xv = xb[t];
        float bur = fmaf(xv, wr, cr), bui = fmaf(xv, wi, ci);
        float nsr = fmaf(lbr, sr, fmaf(-lbi, si, bur));
        float nsi = fmaf(lbr, si, fmaf(lbi, sr, bui));
        sr = nsr; si = nsi;
        xr[(row0 + t) * PDIM + p] = sr;
        xi[(row0 + t) * PDIM + p] = si;
    }
}

// ---- C-projection GEMM + S5 epilogue: h1 = tanh(2*Re(xs C^T) + D*u) + u ----
__global__ __launch_bounds__(256) void k_cgemm(
        const float* __restrict__ xs_re, const float* __restrict__ xs_im,
        const float* __restrict__ C_re, const float* __restrict__ C_im,
        const float* __restrict__ x, const float* __restrict__ l1w,
        const float* __restrict__ l1b, const float* __restrict__ Dv,
        float* __restrict__ h1) {
    __shared__ float aR[16][68], aI[16][68], bR[16][68], bI[16][68];
    const int t = threadIdx.x;
    const int m0 = blockIdx.x * 64, n0 = blockIdx.y * 64;
    const int tx = t & 15, ty = t >> 4;
    const int lrow = t >> 2, lc = t & 3;
    float acc[4][4] = {{0.f}};
    for (int k0 = 0; k0 < PDIM; k0 += 16) {
        float4 va = *(const float4*)(xs_re + (size_t)(m0 + lrow) * PDIM + k0 + lc * 4);
        float4 vA = *(const float4*)(xs_im + (size_t)(m0 + lrow) * PDIM + k0 + lc * 4);
        float4 vb = *(const float4*)(C_re + (size_t)(n0 + lrow) * PDIM + k0 + lc * 4);
        float4 vB = *(const float4*)(C_im + (size_t)(n0 + lrow) * PDIM + k0 + lc * 4);
        __syncthreads();
        aR[lc*4+0][lrow] = va.x; aR[lc*4+1][lrow] = va.y; aR[lc*4+2][lrow] = va.z; aR[lc*4+3][lrow] = va.w;
        aI[lc*4+0][lrow] = vA.x; aI[lc*4+1][lrow] = vA.y; aI[lc*4+2][lrow] = vA.z; aI[lc*4+3][lrow] = vA.w;
        bR[lc*4+0][lrow] = vb.x; bR[lc*4+1][lrow] = vb.y; bR[lc*4+2][lrow] = vb.z; bR[lc*4+3][lrow] = vb.w;
        bI[lc*4+0][lrow] = vB.x; bI[lc*4+1][lrow] = vB.y; bI[lc*4+2][lrow] = vB.z; bI[lc*4+3][lrow] = vB.w;
        __syncthreads();
        #pragma unroll
        for (int k = 0; k < 16; ++k) {
            float4 ar4 = *(const float4*)&aR[k][ty * 4];
            float4 ai4 = *(const float4*)&aI[k][ty * 4];
            float4 br4 = *(const float4*)&bR[k][tx * 4];
            float4 bi4 = *(const float4*)&bI[k][tx * 4];
            float am[4] = {ar4.x, ar4.y, ar4.z, ar4.w};
            float ai_[4] = {ai4.x, ai4.y, ai4.z, ai4.w};
            float bm[4] = {br4.x, br4.y, br4.z, br4.w};
            float bi_[4] = {bi4.x, bi4.y, bi4.z, bi4.w};
            #pragma unroll
            for (int i = 0; i < 4; ++i)
                #pragma unroll
                for (int j = 0; j < 4; ++j)
                    acc[i][j] = fmaf(am[i], bm[j], fmaf(-ai_[i], bi_[j], acc[i][j]));
        }
    }
    #pragma unroll
    for (int i = 0; i < 4; ++i) {
        int m = m0 + ty * 4 + i;
        float xv = x[m];
        float ov[4];
        #pragma unroll
        for (int j = 0; j < 4; ++j) {
            int h = n0 + tx * 4 + j;
            float u = fmaf(xv, l1w[h], l1b[h]);
            float s = fmaf(Dv[h], u, 2.0f * acc[i][j]);
            ov[j] = tanhf(s) + u;
        }
        *(float4*)(h1 + (size_t)m * DIMD + n0 + tx * 4) = make_float4(ov[0], ov[1], ov[2], ov[3]);
    }
}

// ---- fused FFN: h2 = tanh(h1 enc^T + eb) dec^T + db + h1 ; out = h2 . l2w + l2b ----
__global__ __launch_bounds__(256) void k_ff(
        const float* __restrict__ h1, const float* __restrict__ enc_w,
        const float* __restrict__ enc_b, const float* __restrict__ dwt,
        const float* __restrict__ dec_b, const float* __restrict__ l2w,
        const float* __restrict__ l2b, float* __restrict__ out) {
    __shared__ float h1s[32][260];
    __shared__ float fs[32][260];
    const int t = threadIdx.x;
    const int m0 = blockIdx.x * 32;
    #pragma unroll
    for (int e = 0; e < 8; ++e) {
        int f = t + e * 256;
        int row = f >> 6, c4 = f & 63;
        float4 v = *(const float4*)(h1 + (size_t)(m0 + row) * DIMD + c4 * 4);
        *(float4*)&h1s[row][c4 * 4] = v;
    }
    __syncthreads();
    const int kg = t & 31, mg = t >> 5;     // phase 1: thread -> 4 rows x 8 ks
    const int tn4 = t & 63, tm8 = t >> 6;   // phase 2: thread -> 8 rows x 4 cols
    float acc[8][4] = {{0.f}};
    for (int k0 = 0; k0 < FDIM; k0 += 256) {
        // ---- phase 1: f = tanh(h1 @ enc_w^T + enc_b) for 256-wide k chunk ----
        float facc[4][8] = {{0.f}};
        for (int d = 0; d < DIMD; d += 4) {
            float4 hv[4];
            #pragma unroll
            for (int i = 0; i < 4; ++i) hv[i] = *(const float4*)&h1s[mg * 4 + i][d];
            float4 ev[8];
            #pragma unroll
            for (int j = 0; j < 8; ++j)
                ev[j] = *(const float4*)(enc_w + (size_t)(k0 + kg * 8 + j) * DIMD + d);
            #pragma unroll
            for (int i = 0; i < 4; ++i)
                #pragma unroll
                for (int j = 0; j < 8; ++j) {
                    facc[i][j] = fmaf(hv[i].x, ev[j].x, facc[i][j]);
                    facc[i][j] = fmaf(hv[i].y, ev[j].y, facc[i][j]);
                    facc[i][j] = fmaf(hv[i].z, ev[j].z, facc[i][j]);
                    facc[i][j] = fmaf(hv[i].w, ev[j].w, facc[i][j]);
                }
        }
        __syncthreads();   // previous chunk's phase-2 readers done with fs
        #pragma unroll
        for (int i = 0; i < 4; ++i) {
            float4 w0, w1;
            w0.x = tanhf(facc[i][0] + enc_b[k0 + kg * 8 + 0]);
            w0.y = tanhf(facc[i][1] + enc_b[k0 + kg * 8 + 1]);
            w0.z = tanhf(facc[i][2] + enc_b[k0 + kg * 8 + 2]);
            w0.w = tanhf(facc[i][3] + enc_b[k0 + kg * 8 + 3]);
            w1.x = tanhf(facc[i][4] + enc_b[k0 + kg * 8 + 4]);
            w1.y = tanhf(facc[i][5] + enc_b[k0 + kg * 8 + 5]);
            w1.z = tanhf(facc[i][6] + enc_b[k0 + kg * 8 + 6]);
            w1.w = tanhf(facc[i][7] + enc_b[k0 + kg * 8 + 7]);
            *(float4*)&fs[mg * 4 + i][kg * 8] = w0;
            *(float4*)&fs[mg * 4 + i][kg * 8 + 4] = w1;
        }
        __syncthreads();
        // ---- phase 2: acc += f_chunk @ dec_w^T chunk ----
        for (int k = 0; k < 256; k += 4) {
            float4 fv[8];
            #pragma unroll
            for (int i = 0; i < 8; ++i) fv[i] = *(const float4*)&fs[tm8 * 8 + i][k];
            float4 dv[4];
            #pragma unroll
            for (int kk = 0; kk < 4; ++kk)
                dv[kk] = *(const float4*)(dwt + (size_t)(k0 + k + kk) * DIMD + tn4 * 4);
            #pragma unroll
            for (int i = 0; i < 8; ++i) {
                float fx[4] = {fv[i].x, fv[i].y, fv[i].z, fv[i].w};
                #pragma unroll
                for (int kk = 0; kk < 4; ++kk) {
                    acc[i][0] = fmaf(fx[kk], dv[kk].x, acc[i][0]);
                    acc[i][1] = fmaf(fx[kk], dv[kk].y, acc[i][1]);
                    acc[i][2] = fmaf(fx[kk], dv[kk].z, acc[i][2]);
                    acc[i][3] = fmaf(fx[kk], dv[kk].w, acc[i][3]);
                }
            }
        }
    }
    // ---- epilogue: +dec_b + residual, dot with l2w, wave-reduce, store scalar ----
    float l2bv = l2b[0];
    #pragma unroll
    for (int i = 0; i < 8; ++i) {
        float s = 0.f;
        #pragma unroll
        for (int j = 0; j < 4; ++j) {
            int n = tn4 * 4 + j;
            float h2 = acc[i][j] + dec_b[n] + h1s[tm8 * 8 + i][n];
            s = fmaf(h2, l2w[n], s);
        }
        #pragma unroll
        for (int off = 32; off >= 1; off >>= 1) s += __shfl_xor(s, off, 64);
        if (tn4 == 0) out[m0 + tm8 * 8 + i] = s + l2bv;
    }
}

extern "C" void kernel_launch(void* const* d_in, const int* in_sizes, int n_in,
                              void* d_out, int out_size, void* d_ws, size_t ws_size,
                              hipStream_t stream) {
    const float* x       = (const float*)d_in[0];
    const float* l1w     = (const float*)d_in[1];
    const float* l1b     = (const float*)d_in[2];
    const float* lam_re  = (const float*)d_in[3];
    const float* lam_im  = (const float*)d_in[4];
    const float* B_re    = (const float*)d_in[5];
    const float* B_im    = (const float*)d_in[6];
    const float* C_re    = (const float*)d_in[7];
    const float* C_im    = (const float*)d_in[8];
    const float* Dv      = (const float*)d_in[9];
    const float* log_stp = (const float*)d_in[10];
    const float* enc_w   = (const float*)d_in[11];
    const float* enc_b   = (const float*)d_in[12];
    const float* dec_w   = (const float*)d_in[13];
    const float* dec_b   = (const float*)d_in[14];
    const float* l2w     = (const float*)d_in[15];
    const float* l2b     = (const float*)d_in[16];
    float* ws  = (float*)d_ws;
    float* out = (float*)d_out;

    hipLaunchKernelGGL(k_consts, dim3(1), dim3(256), 0, stream,
                       l1w, l1b, lam_re, lam_im, B_re, B_im, log_stp, ws);
    hipLaunchKernelGGL(k_transpose, dim3(80, 8), dim3(256), 0, stream, dec_w, ws + OFF_DWT);
    hipLaunchKernelGGL(k_scanA, dim3(NCHUNK, NB), dim3(256), 0, stream, x, ws);
    hipLaunchKernelGGL(k_scanB, dim3(NB), dim3(256), 0, stream, ws);
    hipLaunchKernelGGL(k_scanC, dim3(NCHUNK, NB), dim3(256), 0, stream, x, ws);
    hipLaunchKernelGGL(k_cgemm, dim3(MTOT / 64, 4), dim3(256), 0, stream,
                       ws + OFF_XS_RE, ws + OFF_XS_IM, C_re, C_im, x, l1w, l1b, Dv, ws + OFF_H1);
    hipLaunchKernelGGL(k_ff, dim3(MTOT / 32), dim3(256), 0, stream,
                       ws + OFF_H1, enc_w, enc_b, ws + OFF_DWT, dec_b, l2w, l2b, out);
}

// Round 2
// 434.812 us; speedup vs baseline: 6.6862x; 6.6862x over previous
//
#include <hip/hip_runtime.h>

#define DIMD 256
#define PDIM 256
#define NB   8
#define LSEQ 4096
#define MTOT (NB*LSEQ)      // 32768
#define FDIM 2560
#define NCHUNK 64
#define CLEN 64

typedef __attribute__((ext_vector_type(8))) short s8bf;   // 8 bf16 = 4 VGPRs
typedef __attribute__((ext_vector_type(4))) float f32x4;

#define MFMA16(a,b,c) __builtin_amdgcn_mfma_f32_16x16x32_bf16((a),(b),(c),0,0,0)

// ---- workspace layout (float offsets) ----
static const size_t OFF_LBR  = 0;      // lam_bar re           [256]
static const size_t OFF_LBI  = 256;    // lam_bar im
static const size_t OFF_A64R = 512;    // lam_bar^64 re
static const size_t OFF_A64I = 768;
static const size_t OFF_WR   = 1024;   // w = B_bar . l1_w
static const size_t OFF_WI   = 1280;
static const size_t OFF_CR   = 1536;   // c = B_bar . l1_b
static const size_t OFF_CI   = 1792;
static const size_t OFF_E_RE   = 4096;                       // chunk end states [8][64][256]
static const size_t OFF_E_IM   = OFF_E_RE   + 131072;
static const size_t OFF_CAR_RE = OFF_E_IM   + 131072;        // chunk carry-in   [8][64][256]
static const size_t OFF_CAR_IM = OFF_CAR_RE + 131072;
static const size_t OFF_XS_RE  = OFF_CAR_IM + 131072;        // xs re [32768][256] f32
static const size_t OFF_XS_IM  = OFF_XS_RE  + 8388608;
static const size_t OFF_H1     = OFF_XS_IM  + 8388608;       // h1 bf16 [32768][256] (4,194,304 floats)
static const size_t OFF_ENC16  = OFF_H1     + 4194304;       // enc_w bf16 [2560][256] (327,680 floats)
static const size_t OFF_DEC16  = OFF_ENC16  + 327680;        // dec_w bf16 [256][2560]
// end = 22,155,264 floats = 88.6 MB

__device__ __forceinline__ ushort f2bf(float f) {
    union { float f; unsigned u; } v; v.f = f;
    unsigned u = v.u;
    return (ushort)((u + 0x7FFFu + ((u >> 16) & 1u)) >> 16);   // RNE
}
__device__ __forceinline__ float bf2f(ushort h) {
    union { unsigned u; float f; } v; v.u = ((unsigned)h) << 16;
    return v.f;
}
__device__ __forceinline__ float fast_tanh(float x) {
    x = fminf(15.f, fmaxf(-15.f, x));
    float e = __expf(2.f * x);
    return (e - 1.f) / (e + 1.f);
}

// ---- per-p constants: lam_bar, lam_bar^64, w, c ----
__global__ void k_consts(const float* __restrict__ l1w, const float* __restrict__ l1b,
                         const float* __restrict__ lam_re, const float* __restrict__ lam_im,
                         const float* __restrict__ B_re, const float* __restrict__ B_im,
                         const float* __restrict__ log_step, float* __restrict__ ws) {
    int p = threadIdx.x;
    float st = expf(log_step[p]);
    float lr = lam_re[p], li = lam_im[p];
    float zr = lr * st, zi = li * st;
    float er = expf(zr);
    float lbr = er * cosf(zi), lbi = er * sinf(zi);
    float den = lr * lr + li * li;
    float nr = lbr - 1.0f, ni = lbi;
    float facr = (nr * lr + ni * li) / den;
    float faci = (ni * lr - nr * li) / den;
    float dwr = 0.f, dwi = 0.f, dbr = 0.f, dbi = 0.f;
    for (int h = 0; h < DIMD; ++h) {
        float br = B_re[p * DIMD + h], bi = B_im[p * DIMD + h];
        float w1 = l1w[h], b1 = l1b[h];
        dwr = fmaf(br, w1, dwr); dwi = fmaf(bi, w1, dwi);
        dbr = fmaf(br, b1, dbr); dbi = fmaf(bi, b1, dbi);
    }
    float wr = facr * dwr - faci * dwi, wi = facr * dwi + faci * dwr;
    float cr = facr * dbr - faci * dbi, ci = facr * dbi + faci * dbr;
    float ar = lbr, ai = lbi;
    for (int s = 0; s < 6; ++s) { float t = ar * ar - ai * ai; ai = 2.f * ar * ai; ar = t; }
    ws[OFF_LBR + p] = lbr;  ws[OFF_LBI + p] = lbi;
    ws[OFF_A64R + p] = ar;  ws[OFF_A64I + p] = ai;
    ws[OFF_WR + p] = wr;    ws[OFF_WI + p] = wi;
    ws[OFF_CR + p] = cr;    ws[OFF_CI + p] = ci;
}

// ---- convert FFN weights to bf16 (both arrays are 655360 elements) ----
__global__ void k_tobf16(const float* __restrict__ enc_w, const float* __restrict__ dec_w,
                         ushort* __restrict__ enc16, ushort* __restrict__ dec16) {
    int i = blockIdx.x * 256 + threadIdx.x;
    enc16[i] = f2bf(enc_w[i]);
    dec16[i] = f2bf(dec_w[i]);
}

// ---- scan pass A ----
__global__ void k_scanA(const float* __restrict__ x, float* __restrict__ ws) {
    int p = threadIdx.x, chunk = blockIdx.x, b = blockIdx.y;
    float lbr = ws[OFF_LBR + p], lbi = ws[OFF_LBI + p];
    float wr = ws[OFF_WR + p], wi = ws[OFF_WI + p];
    float cr = ws[OFF_CR + p], ci = ws[OFF_CI + p];
    const float* xb = x + (size_t)b * LSEQ + chunk * CLEN;
    float sr = 0.f, si = 0.f;
    for (int t = 0; t < CLEN; ++t) {
        float xv = xb[t];
        float bur = fmaf(xv, wr, cr), bui = fmaf(xv, wi, ci);
        float nsr = fmaf(lbr, sr, fmaf(-lbi, si, bur));
        float nsi = fmaf(lbr, si, fmaf(lbi, sr, bui));
        sr = nsr; si = nsi;
    }
    size_t idx = ((size_t)b * NCHUNK + chunk) * PDIM + p;
    ws[OFF_E_RE + idx] = sr; ws[OFF_E_IM + idx] = si;
}

// ---- scan pass B ----
__global__ void k_scanB(float* __restrict__ ws) {
    int p = threadIdx.x, b = blockIdx.x;
    float ar = ws[OFF_A64R + p], ai = ws[OFF_A64I + p];
    float sr = 0.f, si = 0.f;
    for (int c = 0; c < NCHUNK; ++c) {
        size_t idx = ((size_t)b * NCHUNK + c) * PDIM + p;
        ws[OFF_CAR_RE + idx] = sr; ws[OFF_CAR_IM + idx] = si;
        float er = ws[OFF_E_RE + idx], ei = ws[OFF_E_IM + idx];
        float nsr = fmaf(ar, sr, fmaf(-ai, si, er));
        float nsi = fmaf(ar, si, fmaf(ai, sr, ei));
        sr = nsr; si = nsi;
    }
}

// ---- scan pass C ----
__global__ void k_scanC(const float* __restrict__ x, float* __restrict__ ws) {
    int p = threadIdx.x, chunk = blockIdx.x, b = blockIdx.y;
    float lbr = ws[OFF_LBR + p], lbi = ws[OFF_LBI + p];
    float wr = ws[OFF_WR + p], wi = ws[OFF_WI + p];
    float cr = ws[OFF_CR + p], ci = ws[OFF_CI + p];
    size_t cidx = ((size_t)b * NCHUNK + chunk) * PDIM + p;
    float sr = ws[OFF_CAR_RE + cidx], si = ws[OFF_CAR_IM + cidx];
    const float* xb = x + (size_t)b * LSEQ + chunk * CLEN;
    size_t row0 = (size_t)b * LSEQ + chunk * CLEN;
    float* xr = ws + OFF_XS_RE;
    float* xi = ws + OFF_XS_IM;
    for (int t = 0; t < CLEN; ++t) {
        float xv = xb[t];
        float bur = fmaf(xv, wr, cr), bui = fmaf(xv, wi, ci);
        float nsr = fmaf(lbr, sr, fmaf(-lbi, si, bur));
        float nsi = fmaf(lbr, si, fmaf(lbi, sr, bui));
        sr = nsr; si = nsi;
        xr[(row0 + t) * PDIM + p] = sr;
        xi[(row0 + t) * PDIM + p] = si;
    }
}

// ---- C-projection GEMM (fp32) + S5 epilogue -> h1 bf16 ----
__global__ __launch_bounds__(256) void k_cgemm(
        const float* __restrict__ xs_re, const float* __restrict__ xs_im,
        const float* __restrict__ C_re, const float* __restrict__ C_im,
        const float* __restrict__ x, const float* __restrict__ l1w,
        const float* __restrict__ l1b, const float* __restrict__ Dv,
        ushort* __restrict__ h1) {
    __shared__ float aR[16][68], aI[16][68], bR[16][68], bI[16][68];
    const int t = threadIdx.x;
    const int m0 = blockIdx.x * 64, n0 = blockIdx.y * 64;
    const int tx = t & 15, ty = t >> 4;
    const int lrow = t >> 2, lc = t & 3;
    float acc[4][4] = {{0.f}};
    for (int k0 = 0; k0 < PDIM; k0 += 16) {
        float4 va = *(const float4*)(xs_re + (size_t)(m0 + lrow) * PDIM + k0 + lc * 4);
        float4 vA = *(const float4*)(xs_im + (size_t)(m0 + lrow) * PDIM + k0 + lc * 4);
        float4 vb = *(const float4*)(C_re + (size_t)(n0 + lrow) * PDIM + k0 + lc * 4);
        float4 vB = *(const float4*)(C_im + (size_t)(n0 + lrow) * PDIM + k0 + lc * 4);
        __syncthreads();
        aR[lc*4+0][lrow] = va.x; aR[lc*4+1][lrow] = va.y; aR[lc*4+2][lrow] = va.z; aR[lc*4+3][lrow] = va.w;
        aI[lc*4+0][lrow] = vA.x; aI[lc*4+1][lrow] = vA.y; aI[lc*4+2][lrow] = vA.z; aI[lc*4+3][lrow] = vA.w;
        bR[lc*4+0][lrow] = vb.x; bR[lc*4+1][lrow] = vb.y; bR[lc*4+2][lrow] = vb.z; bR[lc*4+3][lrow] = vb.w;
        bI[lc*4+0][lrow] = vB.x; bI[lc*4+1][lrow] = vB.y; bI[lc*4+2][lrow] = vB.z; bI[lc*4+3][lrow] = vB.w;
        __syncthreads();
        #pragma unroll
        for (int k = 0; k < 16; ++k) {
            float4 ar4 = *(const float4*)&aR[k][ty * 4];
            float4 ai4 = *(const float4*)&aI[k][ty * 4];
            float4 br4 = *(const float4*)&bR[k][tx * 4];
            float4 bi4 = *(const float4*)&bI[k][tx * 4];
            float am[4] = {ar4.x, ar4.y, ar4.z, ar4.w};
            float ai_[4] = {ai4.x, ai4.y, ai4.z, ai4.w};
            float bm[4] = {br4.x, br4.y, br4.z, br4.w};
            float bi_[4] = {bi4.x, bi4.y, bi4.z, bi4.w};
            #pragma unroll
            for (int i = 0; i < 4; ++i)
                #pragma unroll
                for (int j = 0; j < 4; ++j)
                    acc[i][j] = fmaf(am[i], bm[j], fmaf(-ai_[i], bi_[j], acc[i][j]));
        }
    }
    #pragma unroll
    for (int i = 0; i < 4; ++i) {
        int m = m0 + ty * 4 + i;
        float xv = x[m];
        ushort ov[4];
        #pragma unroll
        for (int j = 0; j < 4; ++j) {
            int h = n0 + tx * 4 + j;
            float u = fmaf(xv, l1w[h], l1b[h]);
            float s = fmaf(Dv[h], u, 2.0f * acc[i][j]);
            ov[j] = f2bf(fast_tanh(s) + u);
        }
        *(ushort4*)(h1 + (size_t)m * DIMD + n0 + tx * 4) = make_ushort4(ov[0], ov[1], ov[2], ov[3]);
    }
}

// ---- fused FFN, bf16 MFMA: per block 64 rows; chunk FDIM by 128 ----
// phase1: f = tanh(h1 @ enc^T + eb) -> swizzled LDS (bf16)
// phase2: acc += f @ dec^T ; epilogue: +dec_b +res, dot l2w
__global__ __launch_bounds__(512, 4) void k_ff2(
        const ushort* __restrict__ h1g, const ushort* __restrict__ enc16,
        const float* __restrict__ enc_b, const ushort* __restrict__ dec16,
        const float* __restrict__ dec_b, const float* __restrict__ l2w,
        const float* __restrict__ l2b, float* __restrict__ out) {
    __shared__ ushort h1s[64 * 256];   // 32 KB, XOR-swizzled rows (512 B stride)
    __shared__ ushort fs[64 * 128];    // 16 KB, XOR-swizzled rows (256 B stride)
    __shared__ float osum[64];
    const int t = threadIdx.x;
    const int m0 = blockIdx.x * 64;
    const int w = t >> 6, l = t & 63;
    const int lr = l & 15, lg = l >> 4;

    // stage h1 tile (bf16) into swizzled LDS: 4 passes x 512 threads x 16B
    #pragma unroll
    for (int e = 0; e < 4; ++e) {
        int flat = e * 512 + t;
        int row = flat >> 5, unit = flat & 31;
        s8bf v = *(const s8bf*)(h1g + (size_t)(m0 + row) * 256 + unit * 8);
        *(s8bf*)((char*)h1s + row * 512 + ((unit * 16) ^ ((row & 7) << 4))) = v;
    }
    if (t < 64) osum[t] = 0.f;
    __syncthreads();

    const f32x4 fz = {0.f, 0.f, 0.f, 0.f};
    f32x4 acc[4][2];
    #pragma unroll
    for (int mi = 0; mi < 4; ++mi) { acc[mi][0] = fz; acc[mi][1] = fz; }

    const ushort* encBase  = enc16 + (size_t)(w * 16 + lr) * 256;
    const ushort* decBase0 = dec16 + (size_t)(w * 32 + lr) * 2560;
    const ushort* decBase1 = dec16 + (size_t)(w * 32 + 16 + lr) * 2560;

    for (int c = 0; c < 20; ++c) {
        const int k0 = c * 128;
        // ---- phase 1: f chunk [64][128], wave w owns 16 f-cols ----
        f32x4 facc[4] = {fz, fz, fz, fz};
        const ushort* encRow = encBase + (size_t)k0 * 256;
        #pragma unroll
        for (int kd = 0; kd < 8; ++kd) {
            s8bf b = *(const s8bf*)(encRow + kd * 32 + lg * 8);
            #pragma unroll
            for (int mi = 0; mi < 4; ++mi) {
                int row = mi * 16 + lr;
                int kb = kd * 64 + lg * 16;
                s8bf a = *(const s8bf*)((const char*)h1s + row * 512 + (kb ^ ((row & 7) << 4)));
                facc[mi] = MFMA16(a, b, facc[mi]);
            }
        }
        float ebv = enc_b[k0 + w * 16 + lr];
        __syncthreads();                      // prev chunk's phase-2 done reading fs
        #pragma unroll
        for (int mi = 0; mi < 4; ++mi)
            #pragma unroll
            for (int r = 0; r < 4; ++r) {
                int m = mi * 16 + 4 * lg + r;
                int kc = w * 16 + lr;
                *(ushort*)((char*)fs + m * 256 + ((kc * 2) ^ ((m & 7) << 4))) =
                    f2bf(fast_tanh(facc[mi][r] + ebv));
            }
        __syncthreads();                      // fs chunk ready
        // ---- phase 2: acc += f @ dec^T ; wave w owns 32 h2-cols ----
        #pragma unroll
        for (int kk = 0; kk < 4; ++kk) {
            s8bf b0 = *(const s8bf*)(decBase0 + k0 + kk * 32 + lg * 8);
            s8bf b1 = *(const s8bf*)(decBase1 + k0 + kk * 32 + lg * 8);
            #pragma unroll
            for (int mi = 0; mi < 4; ++mi) {
                int row = mi * 16 + lr;
                int kb = kk * 64 + lg * 16;
                s8bf a = *(const s8bf*)((const char*)fs + row * 256 + (kb ^ ((row & 7) << 4)));
                acc[mi][0] = MFMA16(a, b0, acc[mi][0]);
                acc[mi][1] = MFMA16(a, b1, acc[mi][1]);
            }
        }
    }
    // ---- epilogue: +dec_b + residual, dot l2w, reduce ----
    const int n0 = w * 32 + lr, n1 = n0 + 16;
    const float db0 = dec_b[n0], db1 = dec_b[n1];
    const float w0 = l2w[n0], w1 = l2w[n1];
    #pragma unroll
    for (int mi = 0; mi < 4; ++mi)
        #pragma unroll
        for (int r = 0; r < 4; ++r) {
            int m = mi * 16 + 4 * lg + r;
            float r0 = bf2f(*(const ushort*)((const char*)h1s + m * 512 + ((2 * n0) ^ ((m & 7) << 4))));
            float r1 = bf2f(*(const ushort*)((const char*)h1s + m * 512 + ((2 * n1) ^ ((m & 7) << 4))));
            float s = (acc[mi][0][r] + db0 + r0) * w0 + (acc[mi][1][r] + db1 + r1) * w1;
            s += __shfl_xor(s, 1, 16);
            s += __shfl_xor(s, 2, 16);
            s += __shfl_xor(s, 4, 16);
            s += __shfl_xor(s, 8, 16);
            if (lr == 0) atomicAdd(&osum[m], s);
        }
    __syncthreads();
    if (t < 64) out[m0 + t] = osum[t] + l2b[0];
}

extern "C" void kernel_launch(void* const* d_in, const int* in_sizes, int n_in,
                              void* d_out, int out_size, void* d_ws, size_t ws_size,
                              hipStream_t stream) {
    const float* x       = (const float*)d_in[0];
    const float* l1w     = (const float*)d_in[1];
    const float* l1b     = (const float*)d_in[2];
    const float* lam_re  = (const float*)d_in[3];
    const float* lam_im  = (const float*)d_in[4];
    const float* B_re    = (const float*)d_in[5];
    const float* B_im    = (const float*)d_in[6];
    const float* C_re    = (const float*)d_in[7];
    const float* C_im    = (const float*)d_in[8];
    const float* Dv      = (const float*)d_in[9];
    const float* log_stp = (const float*)d_in[10];
    const float* enc_w   = (const float*)d_in[11];
    const float* enc_b   = (const float*)d_in[12];
    const float* dec_w   = (const float*)d_in[13];
    const float* dec_b   = (const float*)d_in[14];
    const float* l2w     = (const float*)d_in[15];
    const float* l2b     = (const float*)d_in[16];
    float* ws  = (float*)d_ws;
    float* out = (float*)d_out;
    ushort* h1_16 = (ushort*)(ws + OFF_H1);
    ushort* enc16 = (ushort*)(ws + OFF_ENC16);
    ushort* dec16 = (ushort*)(ws + OFF_DEC16);

    hipLaunchKernelGGL(k_consts, dim3(1), dim3(256), 0, stream,
                       l1w, l1b, lam_re, lam_im, B_re, B_im, log_stp, ws);
    hipLaunchKernelGGL(k_tobf16, dim3(2560), dim3(256), 0, stream, enc_w, dec_w, enc16, dec16);
    hipLaunchKernelGGL(k_scanA, dim3(NCHUNK, NB), dim3(256), 0, stream, x, ws);
    hipLaunchKernelGGL(k_scanB, dim3(NB), dim3(256), 0, stream, ws);
    hipLaunchKernelGGL(k_scanC, dim3(NCHUNK, NB), dim3(256), 0, stream, x, ws);
    hipLaunchKernelGGL(k_cgemm, dim3(MTOT / 64, 4), dim3(256), 0, stream,
                       ws + OFF_XS_RE, ws + OFF_XS_IM, C_re, C_im, x, l1w, l1b, Dv, h1_16);
    hipLaunchKernelGGL(k_ff2, dim3(MTOT / 64), dim3(512), 0, stream,
                       h1_16, enc16, enc_b, dec16, dec_b, l2w, l2b, out);
}

// Round 7
// 313.047 us; speedup vs baseline: 9.2870x; 1.3890x over previous
//
#include <hip/hip_runtime.h>

#define DIMD 256
#define PDIM 256
#define NB   8
#define LSEQ 4096
#define MTOT (NB*LSEQ)      // 32768
#define FDIM 2560
#define NCHUNK 64
#define CLEN 64

typedef __attribute__((ext_vector_type(8))) short s8bf;   // 8 bf16 = 4 VGPRs
typedef __attribute__((ext_vector_type(4))) float f32x4;

#define MFMA16(a,b,c) __builtin_amdgcn_mfma_f32_16x16x32_bf16((a),(b),(c),0,0,0)

// ---- workspace layout (float offsets) ----
static const size_t OFF_LBR  = 0;      // lam_bar re           [256]
static const size_t OFF_LBI  = 256;    // lam_bar im
static const size_t OFF_A64R = 512;    // lam_bar^64 re
static const size_t OFF_A64I = 768;
static const size_t OFF_WR   = 1024;   // w = B_bar . l1_w
static const size_t OFF_WI   = 1280;
static const size_t OFF_CR   = 1536;   // c = B_bar . l1_b
static const size_t OFF_CI   = 1792;
static const size_t OFF_E_RE   = 4096;                       // chunk end states [8][64][256]
static const size_t OFF_E_IM   = OFF_E_RE   + 131072;
static const size_t OFF_CAR_RE = OFF_E_IM   + 131072;        // chunk carry-in   [8][64][256]
static const size_t OFF_CAR_IM = OFF_CAR_RE + 131072;
static const size_t OFF_H1     = OFF_CAR_IM + 131072;        // h1 bf16 [32768][256] (4,194,304 floats)
static const size_t OFF_ENC16  = OFF_H1     + 4194304;       // enc_w bf16 [2560][256]
static const size_t OFF_DEC16  = OFF_ENC16  + 327680;        // dec_w bf16 [256][2560]
static const size_t OFF_CC16   = OFF_DEC16  + 327680;        // Cc bf16 [256][512] k-interleaved
// end ~ 5.4M floats = 21.6 MB

__device__ __forceinline__ ushort f2bf(float f) {
    union { float f; unsigned u; } v; v.f = f;
    unsigned u = v.u;
    return (ushort)((u + 0x7FFFu + ((u >> 16) & 1u)) >> 16);   // RNE
}
__device__ __forceinline__ float bf2f(ushort h) {
    union { unsigned u; float f; } v; v.u = ((unsigned)h) << 16;
    return v.f;
}
// tanh = 1 - 2/(e^{2x}+1); rcp(inf)=0 -> +1, e^{2x}->0 -> -1: no clamps needed
__device__ __forceinline__ float fast_tanh(float x) {
    float e = __expf(2.f * x);
    return 1.f - 2.f * __builtin_amdgcn_rcpf(e + 1.f);
}
// fs-row swizzle: spreads both read groups (m=lr consecutive) and write groups (m=4*lg+r)
__device__ __forceinline__ int fsw(int m) { return ((m ^ (m >> 2)) & 7) << 4; }

// ---- per-p constants: lam_bar, lam_bar^64, w, c ----
__global__ void k_consts(const float* __restrict__ l1w, const float* __restrict__ l1b,
                         const float* __restrict__ lam_re, const float* __restrict__ lam_im,
                         const float* __restrict__ B_re, const float* __restrict__ B_im,
                         const float* __restrict__ log_step, float* __restrict__ ws) {
    int p = threadIdx.x;
    float st = expf(log_step[p]);
    float lr = lam_re[p], li = lam_im[p];
    float zr = lr * st, zi = li * st;
    float er = expf(zr);
    float lbr = er * cosf(zi), lbi = er * sinf(zi);
    float den = lr * lr + li * li;
    float nr = lbr - 1.0f, ni = lbi;
    float facr = (nr * lr + ni * li) / den;
    float faci = (ni * lr - nr * li) / den;
    float dwr = 0.f, dwi = 0.f, dbr = 0.f, dbi = 0.f;
    for (int h = 0; h < DIMD; ++h) {
        float br = B_re[p * DIMD + h], bi = B_im[p * DIMD + h];
        float w1 = l1w[h], b1 = l1b[h];
        dwr = fmaf(br, w1, dwr); dwi = fmaf(bi, w1, dwi);
        dbr = fmaf(br, b1, dbr); dbi = fmaf(bi, b1, dbi);
    }
    float wr = facr * dwr - faci * dwi, wi = facr * dwi + faci * dwr;
    float cr = facr * dbr - faci * dbi, ci = facr * dbi + faci * dbr;
    float ar = lbr, ai = lbi;
    for (int s = 0; s < 6; ++s) { float t = ar * ar - ai * ai; ai = 2.f * ar * ai; ar = t; }
    ws[OFF_LBR + p] = lbr;  ws[OFF_LBI + p] = lbi;
    ws[OFF_A64R + p] = ar;  ws[OFF_A64I + p] = ai;
    ws[OFF_WR + p] = wr;    ws[OFF_WI + p] = wi;
    ws[OFF_CR + p] = cr;    ws[OFF_CI + p] = ci;
}

// ---- weight prep: enc/dec -> bf16 ; Cc16 k-INTERLEAVED to match xs layout ----
// Cc16[h][2p]   =  2*C_re[h][p]   (pairs with xs k=2p   = re_p)
// Cc16[h][2p+1] = -2*C_im[h][p]   (pairs with xs k=2p+1 = im_p)
__global__ void k_prep(const float* __restrict__ enc_w, const float* __restrict__ dec_w,
                       const float* __restrict__ C_re, const float* __restrict__ C_im,
                       ushort* __restrict__ enc16, ushort* __restrict__ dec16,
                       ushort* __restrict__ cc16) {
    int bid = blockIdx.x, t = threadIdx.x;
    if (bid < 2560) {
        int i = bid * 256 + t;
        enc16[i] = f2bf(enc_w[i]);
        dec16[i] = f2bf(dec_w[i]);
    } else {
        int j = (bid - 2560) * 256 + t;       // 512 blocks -> 131072 = 256*512
        int h = j >> 9, c = j & 511;
        int p = c >> 1;
        float v = ((c & 1) == 0) ? 2.f * C_re[h * 256 + p] : -2.f * C_im[h * 256 + p];
        cc16[j] = f2bf(v);
    }
}

// ---- scan pass A: per (b,chunk,p) chunk-local end state (zero init) ----
__global__ void k_scanA(const float* __restrict__ x, float* __restrict__ ws) {
    int p = threadIdx.x, chunk = blockIdx.x, b = blockIdx.y;
    float lbr = ws[OFF_LBR + p], lbi = ws[OFF_LBI + p];
    float wr = ws[OFF_WR + p], wi = ws[OFF_WI + p];
    float cr = ws[OFF_CR + p], ci = ws[OFF_CI + p];
    const float* xb = x + (size_t)b * LSEQ + chunk * CLEN;
    float sr = 0.f, si = 0.f;
    for (int t = 0; t < CLEN; ++t) {
        float xv = xb[t];
        float bur = fmaf(xv, wr, cr), bui = fmaf(xv, wi, ci);
        float nsr = fmaf(lbr, sr, fmaf(-lbi, si, bur));
        float nsi = fmaf(lbr, si, fmaf(lbi, sr, bui));
        sr = nsr; si = nsi;
    }
    size_t idx = ((size_t)b * NCHUNK + chunk) * PDIM + p;
    ws[OFF_E_RE + idx] = sr; ws[OFF_E_IM + idx] = si;
}

// ---- scan pass B: combine chunks, store carry-in per chunk ----
__global__ void k_scanB(float* __restrict__ ws) {
    int p = threadIdx.x, b = blockIdx.x;
    float ar = ws[OFF_A64R + p], ai = ws[OFF_A64I + p];
    float sr = 0.f, si = 0.f;
    for (int c = 0; c < NCHUNK; ++c) {
        size_t idx = ((size_t)b * NCHUNK + c) * PDIM + p;
        ws[OFF_CAR_RE + idx] = sr; ws[OFF_CAR_IM + idx] = si;
        float er = ws[OFF_E_RE + idx], ei = ws[OFF_E_IM + idx];
        float nsr = fmaf(ar, sr, fmaf(-ai, si, er));
        float nsi = fmaf(ar, si, fmaf(ai, sr, ei));
        sr = nsr; si = nsi;
    }
}

// ---- fused scanC + C-projection (bf16 MFMA) + S5 epilogue -> h1 bf16 ----
// block = one 64-row chunk: 256 threads (4 waves) scan (p-parallel, fp32 state)
// -> xs LDS bf16 (re/im interleaved along k, XOR-swizzled),
// then 4 waves MFMA vs Cc16 [256][512]; wave w owns output cols w*64..w*64+63.
__global__ __launch_bounds__(256) void k_scg(
        const float* __restrict__ x, const float* __restrict__ ws,
        const ushort* __restrict__ cc16, const float* __restrict__ l1w,
        const float* __restrict__ l1b, const float* __restrict__ Dv,
        ushort* __restrict__ h1) {
    __shared__ ushort xs[64 * 512];   // 64 KB: row=t (1024B), col 2p=re, 2p+1=im
    __shared__ float xbuf[64];
    const int t = threadIdx.x;
    const int chunk = blockIdx.x, b = blockIdx.y;
    const size_t row0 = (size_t)b * LSEQ + chunk * CLEN;
    if (t < 64) xbuf[t] = x[row0 + t];
    const int p = t;
    float lbr = ws[OFF_LBR + p], lbi = ws[OFF_LBI + p];
    float wr = ws[OFF_WR + p], wi = ws[OFF_WI + p];
    float cr = ws[OFF_CR + p], ci = ws[OFF_CI + p];
    size_t cidx = ((size_t)b * NCHUNK + chunk) * PDIM + p;
    float sr = ws[OFF_CAR_RE + cidx], si = ws[OFF_CAR_IM + cidx];
    __syncthreads();
    for (int tt = 0; tt < CLEN; ++tt) {
        float xv = xbuf[tt];
        float bur = fmaf(xv, wr, cr), bui = fmaf(xv, wi, ci);
        float nsr = fmaf(lbr, sr, fmaf(-lbi, si, bur));
        float nsi = fmaf(lbr, si, fmaf(lbi, sr, bui));
        sr = nsr; si = nsi;
        unsigned pk;
        asm("v_cvt_pk_bf16_f32 %0, %1, %2" : "=v"(pk) : "v"(sr), "v"(si));
        *(unsigned*)((char*)xs + tt * 1024 + ((p * 4) ^ ((tt & 7) << 4))) = pk;
    }
    __syncthreads();
    // GEMM: out 64x256, K=512
    const int w = t >> 6, l = t & 63, lr = l & 15, lg = l >> 4;
    const f32x4 fz = {0.f, 0.f, 0.f, 0.f};
    f32x4 acc[4][4];
    #pragma unroll
    for (int mi = 0; mi < 4; ++mi)
        #pragma unroll
        for (int nj = 0; nj < 4; ++nj) acc[mi][nj] = fz;
    for (int ks = 0; ks < 16; ++ks) {
        s8bf a[4];
        #pragma unroll
        for (int mi = 0; mi < 4; ++mi) {
            int row = mi * 16 + lr;
            a[mi] = *(const s8bf*)((const char*)xs + row * 1024 + ((ks * 64 + lg * 16) ^ ((row & 7) << 4)));
        }
        #pragma unroll
        for (int nj = 0; nj < 4; ++nj) {
            int n = w * 64 + nj * 16 + lr;
            s8bf bfrag = *(const s8bf*)(cc16 + (size_t)n * 512 + ks * 32 + lg * 8);
            #pragma unroll
            for (int mi = 0; mi < 4; ++mi)
                acc[mi][nj] = MFMA16(a[mi], bfrag, acc[mi][nj]);
        }
    }
    // epilogue: u = x*l1w + l1b ; h1 = tanh(D*u + 2Re(Cx)) + u   (2x folded into Cc16)
    #pragma unroll
    for (int nj = 0; nj < 4; ++nj) {
        int n = w * 64 + nj * 16 + lr;
        float l1wn = l1w[n], l1bn = l1b[n], dn = Dv[n];
        #pragma unroll
        for (int mi = 0; mi < 4; ++mi)
            #pragma unroll
            for (int r = 0; r < 4; ++r) {
                int mrow = mi * 16 + lg * 4 + r;
                float u = fmaf(xbuf[mrow], l1wn, l1bn);
                float s = fmaf(dn, u, acc[mi][nj][r]);
                h1[(row0 + mrow) * DIMD + n] = f2bf(fast_tanh(s) + u);
            }
    }
}

// ---- fused FFN, bf16 MFMA: per block 64 rows, 512 threads = 8 waves ----
// chunk FDIM by 128: phase1 f=tanh(h1 enc^T+eb) -> fs (8 waves x 16 f-cols);
// phase2 acc += f dec^T (8 waves x 32 h2-cols); epilogue +dec_b +res, dot l2w.
__global__ __launch_bounds__(512, 4) void k_ff2(
        const ushort* __restrict__ h1g, const ushort* __restrict__ enc16,
        const float* __restrict__ enc_b, const ushort* __restrict__ dec16,
        const float* __restrict__ dec_b, const float* __restrict__ l2w,
        const float* __restrict__ l2b, float* __restrict__ out) {
    __shared__ ushort h1s[64 * 256];   // 32 KB, XOR-swizzled rows (512 B stride)
    __shared__ ushort fs[64 * 128];    // 16 KB, fsw-swizzled rows (256 B stride)
    __shared__ float osum[64];
    const int t = threadIdx.x;
    const int m0 = blockIdx.x * 64;
    const int w = t >> 6, l = t & 63;
    const int lr = l & 15, lg = l >> 4;

    #pragma unroll
    for (int e = 0; e < 4; ++e) {
        int flat = e * 512 + t;
        int row = flat >> 5, unit = flat & 31;
        s8bf v = *(const s8bf*)(h1g + (size_t)(m0 + row) * 256 + unit * 8);
        *(s8bf*)((char*)h1s + row * 512 + ((unit * 16) ^ ((row & 7) << 4))) = v;
    }
    if (t < 64) osum[t] = 0.f;
    __syncthreads();

    const f32x4 fz = {0.f, 0.f, 0.f, 0.f};
    f32x4 acc[4][2];
    #pragma unroll
    for (int mi = 0; mi < 4; ++mi) { acc[mi][0] = fz; acc[mi][1] = fz; }

    const ushort* encBase  = enc16 + (size_t)(w * 16 + lr) * 256;
    const ushort* decBase0 = dec16 + (size_t)(w * 32 + lr) * 2560;
    const ushort* decBase1 = dec16 + (size_t)(w * 32 + 16 + lr) * 2560;

    for (int c = 0; c < 20; ++c) {
        const int k0 = c * 128;
        // ---- phase 1: f chunk [64][128]; wave w owns f-col k0 + w*16 + lr ----
        f32x4 facc[4] = {fz, fz, fz, fz};
        const ushort* encRow = encBase + (size_t)k0 * 256;
        #pragma unroll
        for (int kd = 0; kd < 8; ++kd) {
            s8bf bfrag = *(const s8bf*)(encRow + kd * 32 + lg * 8);
            #pragma unroll
            for (int mi = 0; mi < 4; ++mi) {
                int row = mi * 16 + lr;
                int kb = kd * 64 + lg * 16;
                s8bf a = *(const s8bf*)((const char*)h1s + row * 512 + (kb ^ ((row & 7) << 4)));
                facc[mi] = MFMA16(a, bfrag, facc[mi]);
            }
        }
        float ebv = enc_b[k0 + w * 16 + lr];
        __syncthreads();                      // prev chunk's phase-2 done reading fs
        #pragma unroll
        for (int mi = 0; mi < 4; ++mi)
            #pragma unroll
            for (int r = 0; r < 4; ++r) {
                int m = mi * 16 + 4 * lg + r;
                int kc = w * 16 + lr;
                *(ushort*)((char*)fs + m * 256 + ((kc * 2) ^ fsw(m))) =
                    f2bf(fast_tanh(facc[mi][r] + ebv));
            }
        __syncthreads();                      // fs chunk ready
        // ---- phase 2: acc += f @ dec^T ; wave w owns h2-cols w*32+{0..15,16..31} ----
        #pragma unroll
        for (int kk = 0; kk < 4; ++kk) {
            s8bf b0 = *(const s8bf*)(decBase0 + k0 + kk * 32 + lg * 8);
            s8bf b1 = *(const s8bf*)(decBase1 + k0 + kk * 32 + lg * 8);
            #pragma unroll
            for (int mi = 0; mi < 4; ++mi) {
                int row = mi * 16 + lr;
                int kb = kk * 64 + lg * 16;
                s8bf a = *(const s8bf*)((const char*)fs + row * 256 + (kb ^ fsw(row)));
                acc[mi][0] = MFMA16(a, b0, acc[mi][0]);
                acc[mi][1] = MFMA16(a, b1, acc[mi][1]);
            }
        }
    }
    // ---- epilogue: +dec_b + residual, dot l2w, reduce ----
    const int n0 = w * 32 + lr, n1 = n0 + 16;
    const float db0 = dec_b[n0], db1 = dec_b[n1];
    const float w0 = l2w[n0], w1 = l2w[n1];
    #pragma unroll
    for (int mi = 0; mi < 4; ++mi)
        #pragma unroll
        for (int r = 0; r < 4; ++r) {
            int m = mi * 16 + 4 * lg + r;
            float r0 = bf2f(*(const ushort*)((const char*)h1s + m * 512 + ((2 * n0) ^ ((m & 7) << 4))));
            float r1 = bf2f(*(const ushort*)((const char*)h1s + m * 512 + ((2 * n1) ^ ((m & 7) << 4))));
            float s = (acc[mi][0][r] + db0 + r0) * w0 + (acc[mi][1][r] + db1 + r1) * w1;
            s += __shfl_xor(s, 1, 16);
            s += __shfl_xor(s, 2, 16);
            s += __shfl_xor(s, 4, 16);
            s += __shfl_xor(s, 8, 16);
            if (lr == 0) atomicAdd(&osum[m], s);
        }
    __syncthreads();
    if (t < 64) out[m0 + t] = osum[t] + l2b[0];
}

extern "C" void kernel_launch(void* const* d_in, const int* in_sizes, int n_in,
                              void* d_out, int out_size, void* d_ws, size_t ws_size,
                              hipStream_t stream) {
    const float* x       = (const float*)d_in[0];
    const float* l1w     = (const float*)d_in[1];
    const float* l1b     = (const float*)d_in[2];
    const float* lam_re  = (const float*)d_in[3];
    const float* lam_im  = (const float*)d_in[4];
    const float* B_re    = (const float*)d_in[5];
    const float* B_im    = (const float*)d_in[6];
    const float* C_re    = (const float*)d_in[7];
    const float* C_im    = (const float*)d_in[8];
    const float* Dv      = (const float*)d_in[9];
    const float* log_stp = (const float*)d_in[10];
    const float* enc_w   = (const float*)d_in[11];
    const float* enc_b   = (const float*)d_in[12];
    const float* dec_w   = (const float*)d_in[13];
    const float* dec_b   = (const float*)d_in[14];
    const float* l2w     = (const float*)d_in[15];
    const float* l2b     = (const float*)d_in[16];
    float* ws  = (float*)d_ws;
    float* out = (float*)d_out;
    ushort* h1_16 = (ushort*)(ws + OFF_H1);
    ushort* enc16 = (ushort*)(ws + OFF_ENC16);
    ushort* dec16 = (ushort*)(ws + OFF_DEC16);
    ushort* cc16  = (ushort*)(ws + OFF_CC16);

    hipLaunchKernelGGL(k_consts, dim3(1), dim3(256), 0, stream,
                       l1w, l1b, lam_re, lam_im, B_re, B_im, log_stp, ws);
    hipLaunchKernelGGL(k_prep, dim3(3072), dim3(256), 0, stream,
                       enc_w, dec_w, C_re, C_im, enc16, dec16, cc16);
    hipLaunchKernelGGL(k_scanA, dim3(NCHUNK, NB), dim3(256), 0, stream, x, ws);
    hipLaunchKernelGGL(k_scanB, dim3(NB), dim3(256), 0, stream, ws);
    hipLaunchKernelGGL(k_scg, dim3(NCHUNK, NB), dim3(256), 0, stream,
                       x, ws, cc16, l1w, l1b, Dv, h1_16);
    hipLaunchKernelGGL(k_ff2, dim3(MTOT / 64), dim3(512), 0, stream,
                       h1_16, enc16, enc_b, dec16, dec_b, l2w, l2b, out);
}